// Round 7
// baseline (315.204 us; speedup 1.0000x reference)
//
#include <hip/hip_runtime.h>
#include <hip/hip_fp16.h>

#define HDIM 256
#define MS 8
#define LDAK 264   // 256 + 8 halves pad

typedef _Float16 half8 __attribute__((ext_vector_type(8)));
typedef _Float16 half4 __attribute__((ext_vector_type(4)));
typedef _Float16 half2v __attribute__((ext_vector_type(2)));
typedef float f32x4 __attribute__((ext_vector_type(4)));

__device__ __forceinline__ float fast_tanh(float x) {
    float e = __expf(2.0f * x);
    return 1.0f - 2.0f * __builtin_amdgcn_rcpf(e + 1.0f);
}

__device__ __forceinline__ half4 cvt4(float a, float b, float c, float d) {
    half2v lo = __builtin_bit_cast(half2v, __builtin_amdgcn_cvt_pkrtz(a, b));
    half2v hi = __builtin_bit_cast(half2v, __builtin_amdgcn_cvt_pkrtz(c, d));
    half4 r; r[0] = lo[0]; r[1] = lo[1]; r[2] = hi[0]; r[3] = hi[1];
    return r;
}

// lane i <- lane (i^8) within each 16-lane DPP row (ROW_ROR:8). Pure VALU.
__device__ __forceinline__ float dpp_xor8(float v) {
    int r = __builtin_amdgcn_update_dpp(0, __builtin_bit_cast(int, v),
                                        0x128, 0xf, 0xf, true);
    return __builtin_bit_cast(float, r);
}

// Pack W1,W2,W3 (fp32 [256][256], row=k, col=n) into f16 frag layout:
// Wp[l][ ((k>>3)*256 + n)*8 + (k&7) ].
__global__ __launch_bounds__(256) void pack_weights(const float* __restrict__ W1,
                                                    const float* __restrict__ W2,
                                                    const float* __restrict__ W3,
                                                    _Float16* __restrict__ out) {
    int tid = blockIdx.x * 256 + threadIdx.x;  // 0..24575
    int l = tid >> 13;
    int idx = tid & 8191;   // kg*256 + n
    int kg = idx >> 8;
    int n = idx & 255;
    const float* W = (l == 0) ? W1 : (l == 1) ? W2 : W3;
    half8 v;
    #pragma unroll
    for (int j = 0; j < 8; ++j) v[j] = (_Float16)W[(kg * 8 + j) * 256 + n];
    *(half8*)(out + l * 65536 + (kg * 256 + n) * 8) = v;
}

// Row layout: row = c*8 + m, c in 0..7 (c=7 zero pad), m in 0..7.
// M-tile T (16 rows) = channels {2T, 2T+1} x 8 samples. Coupling lanes: n15 ^ 8.
__global__ __launch_bounds__(256, 3)
void pinn_fused(const float* __restrict__ x,
                const float* __restrict__ W0,
                const float* __restrict__ b0,
                const float* __restrict__ b1,
                const float* __restrict__ b2,
                const float* __restrict__ b3,
                const float* __restrict__ Wout,
                const float* __restrict__ bout,
                const _Float16* __restrict__ Wp,
                float* __restrict__ out) {
    __shared__ __align__(16) _Float16 Abuf[8 * MS][LDAK];  // 64 rows x 264, 33 KB
    __shared__ float xs[MS * 3];

    const int tid  = threadIdx.x;
    const int lane = tid & 63;
    const int wid  = tid >> 6;        // wave 0..3 -> n-strip base wid*64
    const int qd   = lane >> 4;
    const int n15  = lane & 15;
    const bool ev  = (lane & 8) == 0; // even channel of the pair
    const int base = blockIdx.x * MS;
    const int nw   = wid * 64 + n15;

    if (tid < MS * 3) xs[tid] = x[base * 3 + tid];

    // 2-deep W prefetch over flat step g = l*8+s (24 steps); g=0 issued now.
    half8 wf[2][4];
    #pragma unroll
    for (int t = 0; t < 4; ++t)
        wf[0][t] = *(const half8*)(Wp + ((0 * 4 + qd) * 256 + nw + t * 16) * 8);

    __syncthreads();   // xs ready

    // ---------------- layer 0: 3 -> 256, jets analytic ----------------
    {
        const int m  = tid >> 5;          // sample 0..7
        const int n0 = (tid & 31) * 8;    // 8 consecutive n
        const float x0 = xs[m * 3 + 0], x1 = xs[m * 3 + 1], x2 = xs[m * 3 + 2];
        half8 h[7];
        #pragma unroll
        for (int r = 0; r < 8; ++r) {
            const int n = n0 + r;
            const float w0 = W0[n], w1 = W0[HDIM + n], w2 = W0[2 * HDIM + n];
            float z  = x0 * w0 + x1 * w1 + x2 * w2 + b0[n];
            float tv = fast_tanh(z);
            float dd = 1.f - tv * tv;
            float c2 = -2.f * tv * dd;
            h[0][r] = (_Float16)tv;
            h[1][r] = (_Float16)(dd * w0);
            h[2][r] = (_Float16)(dd * w1);
            h[3][r] = (_Float16)(dd * w2);
            h[4][r] = (_Float16)(c2 * w0 * w0);
            h[5][r] = (_Float16)(c2 * w1 * w1);
            h[6][r] = (_Float16)(c2 * w2 * w2);
        }
        #pragma unroll
        for (int c = 0; c < 7; ++c)
            *(half8*)&Abuf[c * 8 + m][n0] = h[c];
        *(half8*)&Abuf[56 + m][n0] = (half8)(_Float16)0.f;   // pad channel = 0
    }
    __syncthreads();

    // ---------------- layers 1..3: transposed MFMA (Z^T = W^T A^T) ----------------
    #pragma unroll
    for (int l = 0; l < 3; ++l) {
        const float* bb = (l == 0) ? b1 : (l == 1) ? b2 : b3;

        f32x4 acc[4][4];   // [Mtile][Ntile]
        #pragma unroll
        for (int T = 0; T < 4; ++T)
            #pragma unroll
            for (int t = 0; t < 4; ++t) acc[T][t] = (f32x4){0.f, 0.f, 0.f, 0.f};

        #pragma unroll
        for (int s = 0; s < 8; ++s) {
            const int g = l * 8 + s;
            if (g + 1 < 24) {   // prefetch next step's W frags
                const _Float16* Wn = Wp + ((g + 1) >> 3) * 65536;
                const int sn = (g + 1) & 7;
                #pragma unroll
                for (int t = 0; t < 4; ++t)
                    wf[(g + 1) & 1][t] =
                        *(const half8*)(Wn + ((sn * 4 + qd) * 256 + nw + t * 16) * 8);
            }
            half8 af[4];
            #pragma unroll
            for (int T = 0; T < 4; ++T)
                af[T] = *(const half8*)&Abuf[T * 16 + n15][s * 32 + qd * 8];
            #pragma unroll
            for (int T = 0; T < 4; ++T)
                #pragma unroll
                for (int t = 0; t < 4; ++t)
                    acc[T][t] = __builtin_amdgcn_mfma_f32_16x16x32_f16(wf[g & 1][t], af[T], acc[T][t], 0, 0, 0);
        }
        __syncthreads();  // all waves done reading Abuf

        // Elem: lane holds Z rows {T*16+n15} at cols ncol..ncol+3.
        // even lane (n15<8): channels {0,2,4,6}; odd: {1,3,5,7=pad}.
        #pragma unroll
        for (int t = 0; t < 4; ++t) {
            const int ncol = wid * 64 + t * 16 + qd * 4;
            f32x4 bv = *(const f32x4*)(bb + ncol);
            float o0[4], o1[4], o2[4], o3[4];
            #pragma unroll
            for (int r = 0; r < 4; ++r) {
                float a0 = acc[0][t][r], a1 = acc[1][t][r];
                float a2 = acc[2][t][r], a3 = acc[3][t][r];
                float zv = a0 + (ev ? bv[r] : 0.f);
                float tv = fast_tanh(zv);
                float dd = 1.f - tv * tv;
                float c2 = -2.f * tv * dd;
                float P0 = dpp_xor8(a0);   // even <- zg1 (odd's a0)
                float P1 = dpp_xor8(a1);   // even <- zg3, odd <- zg2
                float Pd = dpp_xor8(dd);   // odd <- true d
                float Pc = dpp_xor8(c2);   // odd <- true c2
                float dU = ev ? dd : Pd;
                float cU = ev ? c2 : Pc;
                float zgA = ev ? P0 : P1;
                o0[r] = ev ? tv : dU * a0;              // c0: value | c1: grad1
                o1[r] = dU * a1;                        // c2: grad2 | c3: grad3
                o2[r] = dU * a2 + cU * zgA * zgA;       // c4: hess1 | c5: hess2
                o3[r] = ev ? (dU * a3 + cU * P1 * P1)   // c6: hess3
                           : 0.f;                       // c7: pad stays 0
            }
            *(half4*)&Abuf[0 * 16 + n15][ncol] = cvt4(o0[0], o0[1], o0[2], o0[3]);
            *(half4*)&Abuf[1 * 16 + n15][ncol] = cvt4(o1[0], o1[1], o1[2], o1[3]);
            *(half4*)&Abuf[2 * 16 + n15][ncol] = cvt4(o2[0], o2[1], o2[2], o2[3]);
            *(half4*)&Abuf[3 * 16 + n15][ncol] = cvt4(o3[0], o3[1], o3[2], o3[3]);
        }
        __syncthreads();
    }

    // ---------------- output: 56 rows x 256 dot Wout; 4 threads/row ----------------
    if (tid < 56 * 4) {
        const int row = tid >> 2;        // 0..55 = c*8+m
        const int q   = tid & 3;
        const _Float16* rp = &Abuf[row][q * 64];
        const float* wp = Wout + q * 64;
        float accv = 0.f;
        #pragma unroll
        for (int kg = 0; kg < 8; ++kg) {
            half8 av = *(const half8*)&rp[kg * 8];
            #pragma unroll
            for (int j = 0; j < 8; ++j) accv += (float)av[j] * wp[kg * 8 + j];
        }
        accv += __shfl_xor(accv, 1, 64);
        accv += __shfl_xor(accv, 2, 64);
        if (q == 0) {
            const int c = row >> 3;
            const int m = row & 7;
            if (c == 0) accv += bout[0];
            out[(base + m) * 7 + c] = accv;
        }
    }
}

extern "C" void kernel_launch(void* const* d_in, const int* in_sizes, int n_in,
                              void* d_out, int out_size, void* d_ws, size_t ws_size,
                              hipStream_t stream) {
    const float* xp   = (const float*)d_in[0];
    const float* W0   = (const float*)d_in[1];
    const float* b0   = (const float*)d_in[2];
    const float* W1   = (const float*)d_in[3];
    const float* b1   = (const float*)d_in[4];
    const float* W2   = (const float*)d_in[5];
    const float* b2   = (const float*)d_in[6];
    const float* W3   = (const float*)d_in[7];
    const float* b3   = (const float*)d_in[8];
    const float* Wout = (const float*)d_in[9];
    const float* bout = (const float*)d_in[10];
    _Float16* Wp = (_Float16*)d_ws;  // 3 * 65536 halves = 384 KB

    pack_weights<<<96, 256, 0, stream>>>(W1, W2, W3, Wp);
    pinn_fused<<<65536 / MS, 256, 0, stream>>>(xp, W0, b0, b1, b2, b3, Wout, bout, Wp,
                                               (float*)d_out);
}

// Round 8
// 276.604 us; speedup vs baseline: 1.1395x; 1.1395x over previous
//
#include <hip/hip_runtime.h>
#include <hip/hip_fp16.h>

#define HDIM 256
#define MS 16

typedef _Float16 half8 __attribute__((ext_vector_type(8)));
typedef _Float16 half4 __attribute__((ext_vector_type(4)));
typedef _Float16 half2v __attribute__((ext_vector_type(2)));
typedef float f32x4 __attribute__((ext_vector_type(4)));

__device__ __forceinline__ float fast_tanh(float x) {
    // tanh(x) = 1 - 2/(e^{2x}+1); v_exp-based, graceful at +-inf
    float e = __expf(2.0f * x);
    return 1.0f - 2.0f * __builtin_amdgcn_rcpf(e + 1.0f);
}

__device__ __forceinline__ half4 cvt4(float a, float b, float c, float d) {
    half2v lo = __builtin_bit_cast(half2v, __builtin_amdgcn_cvt_pkrtz(a, b));
    half2v hi = __builtin_bit_cast(half2v, __builtin_amdgcn_cvt_pkrtz(c, d));
    half4 r; r[0] = lo[0]; r[1] = lo[1]; r[2] = hi[0]; r[3] = hi[1];
    return r;
}

// Additive bank rotation: row stride 256 halves (512 B, bank-aligned); rotate
// the 16B-group index (5 bits) by row*4 mod 32. K-loop b128 reads: groups
// (s*4+qd+4*n15)%32 -> 32 banks, 2-lane broadcast (free). Elem b64 writes:
// 32 distinct bank-pairs, 2-way (free). Bijective per row.
__device__ __forceinline__ int swz(int row, int col) {
    return (col & 7) | ((((col >> 3) + (row << 2)) & 31) << 3);
}

// Pack W1,W2,W3 (fp32 [256][256], row=k, col=n) into f16 frag layout:
// Wp[l][ ((k>>3)*256 + n)*8 + (k&7) ].
__global__ __launch_bounds__(256) void pack_weights(const float* __restrict__ W1,
                                                    const float* __restrict__ W2,
                                                    const float* __restrict__ W3,
                                                    _Float16* __restrict__ out) {
    int tid = blockIdx.x * 256 + threadIdx.x;  // 0..24575
    int l = tid >> 13;
    int idx = tid & 8191;   // kg*256 + n
    int kg = idx >> 8;
    int n = idx & 255;
    const float* W = (l == 0) ? W1 : (l == 1) ? W2 : W3;
    half8 v;
    #pragma unroll
    for (int j = 0; j < 8; ++j) v[j] = (_Float16)W[(kg * 8 + j) * 256 + n];
    *(half8*)(out + l * 65536 + (kg * 256 + n) * 8) = v;
}

__global__ __launch_bounds__(256, 2)
void pinn_fused(const float* __restrict__ x,
                const float* __restrict__ W0,
                const float* __restrict__ b0,
                const float* __restrict__ b1,
                const float* __restrict__ b2,
                const float* __restrict__ b3,
                const float* __restrict__ Wout,
                const float* __restrict__ bout,
                const _Float16* __restrict__ Wp,
                float* __restrict__ out) {
    // A: stacked [7 channels x 16 samples] rows x 256 k, f16, swizzled flat
    __shared__ __align__(16) _Float16 Abuf[7 * MS * HDIM];   // 56 KB
    __shared__ float xs[MS * 3];

    const int tid  = threadIdx.x;
    const int lane = tid & 63;
    const int wid  = tid >> 6;        // wave 0..3 -> n-strip base wid*64
    const int qd   = lane >> 4;
    const int n15  = lane & 15;
    const int base = blockIdx.x * MS;
    const int nw   = wid * 64 + n15;

    if (tid < MS * 3) xs[tid] = x[base * 3 + tid];

    // 3-deep W pipeline over flat step g = l*8+s (24 steps); g=0,1 issued now
    // so the L2 reads overlap layer-0 math.
    half8 wf[3][4];
    #pragma unroll
    for (int t = 0; t < 4; ++t)
        wf[0][t] = *(const half8*)(Wp + ((0 * 4 + qd) * 256 + nw + t * 16) * 8);
    #pragma unroll
    for (int t = 0; t < 4; ++t)
        wf[1][t] = *(const half8*)(Wp + ((1 * 4 + qd) * 256 + nw + t * 16) * 8);

    __syncthreads();   // xs ready

    // ---------------- layer 0: 3 -> 256, jets analytic; b128 writes ----------------
    {
        const int m  = tid & 15;
        const int nb = (tid >> 4) * 16;   // 16 consecutive n per thread, 2 chunks
        const float x0 = xs[m * 3 + 0], x1 = xs[m * 3 + 1], x2 = xs[m * 3 + 2];
        #pragma unroll
        for (int ch = 0; ch < 2; ++ch) {
            const int n0 = nb + ch * 8;
            half8 h[7];
            #pragma unroll
            for (int r = 0; r < 8; ++r) {
                const int n = n0 + r;
                const float w0 = W0[n], w1 = W0[HDIM + n], w2 = W0[2 * HDIM + n];
                float z  = x0 * w0 + x1 * w1 + x2 * w2 + b0[n];
                float tv = fast_tanh(z);
                float dd = 1.f - tv * tv;
                float c2 = -2.f * tv * dd;
                h[0][r] = (_Float16)tv;
                h[1][r] = (_Float16)(dd * w0);
                h[2][r] = (_Float16)(dd * w1);
                h[3][r] = (_Float16)(dd * w2);
                h[4][r] = (_Float16)(c2 * w0 * w0);
                h[5][r] = (_Float16)(c2 * w1 * w1);
                h[6][r] = (_Float16)(c2 * w2 * w2);
            }
            #pragma unroll
            for (int c = 0; c < 7; ++c) {
                const int row = c * MS + m;
                *(half8*)&Abuf[row * HDIM + swz(row, n0)] = h[c];
            }
        }
    }
    __syncthreads();

    // ---------------- layers 1..3: transposed MFMA (Z^T = W^T A^T) ----------------
    #pragma unroll
    for (int l = 0; l < 3; ++l) {
        const float* bb = (l == 0) ? b1 : (l == 1) ? b2 : b3;

        f32x4 acc[7][4];
        #pragma unroll
        for (int c = 0; c < 7; ++c)
            #pragma unroll
            for (int t = 0; t < 4; ++t) acc[c][t] = (f32x4){0.f, 0.f, 0.f, 0.f};

        #pragma unroll
        for (int s = 0; s < 8; ++s) {
            const int g = l * 8 + s;
            if (g + 2 < 24) {   // prefetch step g+2's W frags
                const _Float16* Wn = Wp + ((g + 2) >> 3) * 65536;
                const int sn = (g + 2) & 7;
                #pragma unroll
                for (int t = 0; t < 4; ++t)
                    wf[(g + 2) % 3][t] =
                        *(const half8*)(Wn + ((sn * 4 + qd) * 256 + nw + t * 16) * 8);
            }
            half8 af[7];
            #pragma unroll
            for (int c = 0; c < 7; ++c) {
                const int row = c * MS + n15;
                af[c] = *(const half8*)&Abuf[row * HDIM + swz(row, s * 32 + qd * 8)];
            }
            #pragma unroll
            for (int c = 0; c < 7; ++c)
                #pragma unroll
                for (int t = 0; t < 4; ++t)
                    acc[c][t] = __builtin_amdgcn_mfma_f32_16x16x32_f16(wf[g % 3][t], af[c], acc[c][t], 0, 0, 0);
        }
        __syncthreads();  // all waves done reading Abuf

        // lane holds Z[m = n15][n = wid*64 + t*16 + qd*4 + r], r=0..3
        #pragma unroll
        for (int t = 0; t < 4; ++t) {
            const int ncol = wid * 64 + t * 16 + qd * 4;
            f32x4 bv = *(const f32x4*)(bb + ncol);
            float tv[4], gj[3][4], sj[3][4];
            #pragma unroll
            for (int r = 0; r < 4; ++r) {
                float zv = acc[0][t][r] + bv[r];
                tv[r] = fast_tanh(zv);
                float dd = 1.f - tv[r] * tv[r];
                float c2 = -2.f * tv[r] * dd;
                #pragma unroll
                for (int i = 0; i < 3; ++i) {
                    float zg = acc[1 + i][t][r];
                    float zs = acc[4 + i][t][r];
                    gj[i][r] = dd * zg;
                    sj[i][r] = dd * zs + c2 * zg * zg;
                }
            }
            {
                const int row = 0 * MS + n15;
                *(half4*)&Abuf[row * HDIM + swz(row, ncol)] = cvt4(tv[0], tv[1], tv[2], tv[3]);
            }
            #pragma unroll
            for (int i = 0; i < 3; ++i) {
                const int rg = (1 + i) * MS + n15;
                *(half4*)&Abuf[rg * HDIM + swz(rg, ncol)] = cvt4(gj[i][0], gj[i][1], gj[i][2], gj[i][3]);
                const int rs = (4 + i) * MS + n15;
                *(half4*)&Abuf[rs * HDIM + swz(rs, ncol)] = cvt4(sj[i][0], sj[i][1], sj[i][2], sj[i][3]);
            }
        }
        __syncthreads();
    }

    // ---------------- output: 112 rows x 256 dot Wout; 2 threads/row ----------------
    if (tid < 7 * MS * 2) {
        const int row = tid >> 1;        // 0..111
        const int h   = tid & 1;
        const float* wp = Wout + h * 128;
        float accv = 0.f;
        #pragma unroll 4
        for (int kg = 0; kg < 16; ++kg) {
            const int col = h * 128 + kg * 8;
            half8 av = *(const half8*)&Abuf[row * HDIM + swz(row, col)];
            #pragma unroll
            for (int j = 0; j < 8; ++j) accv += (float)av[j] * wp[kg * 8 + j];
        }
        accv += __shfl_xor(accv, 1, 64);
        if (h == 0) {
            const int c = row >> 4;
            const int m = row & 15;
            if (c == 0) accv += bout[0];
            out[(base + m) * 7 + c] = accv;
        }
    }
}

extern "C" void kernel_launch(void* const* d_in, const int* in_sizes, int n_in,
                              void* d_out, int out_size, void* d_ws, size_t ws_size,
                              hipStream_t stream) {
    const float* xp   = (const float*)d_in[0];
    const float* W0   = (const float*)d_in[1];
    const float* b0   = (const float*)d_in[2];
    const float* W1   = (const float*)d_in[3];
    const float* b1   = (const float*)d_in[4];
    const float* W2   = (const float*)d_in[5];
    const float* b2   = (const float*)d_in[6];
    const float* W3   = (const float*)d_in[7];
    const float* b3   = (const float*)d_in[8];
    const float* Wout = (const float*)d_in[9];
    const float* bout = (const float*)d_in[10];
    _Float16* Wp = (_Float16*)d_ws;  // 3 * 65536 halves = 384 KB

    pack_weights<<<96, 256, 0, stream>>>(W1, W2, W3, Wp);
    pinn_fused<<<65536 / MS, 256, 0, stream>>>(xp, W0, b0, b1, b2, b3, Wout, bout, Wp,
                                               (float*)d_out);
}